// Round 1
// baseline (213.136 us; speedup 1.0000x reference)
//
#include <hip/hip_runtime.h>

typedef __bf16 bf16x8 __attribute__((ext_vector_type(8)));
typedef float f32x4 __attribute__((ext_vector_type(4)));

__device__ __forceinline__ unsigned short f2b(float f) {
  union { float f; unsigned int u; } v;
  v.f = f;
  unsigned int r = v.u + 0x7fffu + ((v.u >> 16) & 1u);
  return (unsigned short)(r >> 16);
}

// ---------------- kernel 0: weight f32 -> bf16 (flat [O][C*9]) ----------------
__global__ __launch_bounds__(256) void cast_weight(
    const float* __restrict__ w, unsigned short* __restrict__ wb) {
  int i = blockIdx.x * 256 + threadIdx.x;  // 147456 iters, 4 elems each
  float4 v = ((const float4*)w)[i];
  uint2 p;
  p.x = (unsigned)f2b(v.x) | ((unsigned)f2b(v.y) << 16);
  p.y = (unsigned)f2b(v.z) | ((unsigned)f2b(v.w) << 16);
  ((uint2*)wb)[i] = p;
}

// ---------------- kernel 1: bilinear sample + mask -> colT[b][hw][ck] bf16 ----
// block = (b, output row h, c-quarter of 64). 256 threads = 4 waves, lanes = w.
// LDS stride 67 halves (odd) to spread banks on the transposed read.
__global__ __launch_bounds__(256) void dcn_sample(
    const float* __restrict__ x, const float* __restrict__ off,
    const float* __restrict__ mask, unsigned short* __restrict__ colT) {
  const int bid = blockIdx.x;
  const int b = bid >> 8;
  const int r = bid & 255;
  const int h = r >> 2;
  const int cq = r & 3;
  const int t = threadIdx.x;
  const int wave = t >> 6;
  const int lane = t & 63;
  const int w = lane;

  // per-k tap indices (clamped) and weights (bilinear * valid * mask)
  int idx[9][4];
  float wt[9][4];
  {
    const float* offb = off + (size_t)b * 18 * 4096 + h * 64 + w;
    const float* mb = mask + (size_t)b * 9 * 4096 + h * 64 + w;
#pragma unroll
    for (int k = 0; k < 9; ++k) {
      float oy = offb[(2 * k) * 4096];
      float ox = offb[(2 * k + 1) * 4096];
      float m = mb[k * 4096];
      float py = oy + (float)(h - 1 + k / 3);
      float px = ox + (float)(w - 1 + k % 3);
      float y0f = floorf(py), x0f = floorf(px);
      float ly = py - y0f, lx = px - x0f;
      float hy = 1.f - ly, hx = 1.f - lx;
      int y0 = (int)y0f, x0 = (int)x0f;
      int y1 = y0 + 1, x1 = x0 + 1;
      bool vy0 = (y0 >= 0) && (y0 < 64);
      bool vy1 = (y1 >= 0) && (y1 < 64);
      bool vx0 = (x0 >= 0) && (x0 < 64);
      bool vx1 = (x1 >= 0) && (x1 < 64);
      int yc0 = min(max(y0, 0), 63), yc1 = min(max(y1, 0), 63);
      int xc0 = min(max(x0, 0), 63), xc1 = min(max(x1, 0), 63);
      idx[k][0] = yc0 * 64 + xc0; wt[k][0] = (vy0 && vx0) ? hy * hx * m : 0.f;
      idx[k][1] = yc0 * 64 + xc1; wt[k][1] = (vy0 && vx1) ? hy * lx * m : 0.f;
      idx[k][2] = yc1 * 64 + xc0; wt[k][2] = (vy1 && vx0) ? ly * hx * m : 0.f;
      idx[k][3] = yc1 * 64 + xc1; wt[k][3] = (vy1 && vx1) ? ly * lx * m : 0.f;
    }
  }

  __shared__ __align__(16) unsigned short val_lds[288 * 67];

  const float* xb = x + ((size_t)b * 256 + cq * 64) * 4096;
  const size_t rowbase = ((size_t)b * 4096 + (size_t)h * 64) * 2304 + (size_t)cq * 576;

  for (int half = 0; half < 2; ++half) {
    const int cc0 = half * 32;
    // fill: each wave owns 8 contiguous cc rows; lanes across hw -> conflict-free writes
#pragma unroll
    for (int i = 0; i < 8; ++i) {
      const int cc = wave * 8 + i;  // 0..31
      const float* xp = xb + (size_t)(cc0 + cc) * 4096;
#pragma unroll
      for (int k = 0; k < 9; ++k) {
        float v = wt[k][0] * xp[idx[k][0]] + wt[k][1] * xp[idx[k][1]] +
                  wt[k][2] * xp[idx[k][2]] + wt[k][3] * xp[idx[k][3]];
        val_lds[(cc * 9 + k) * 67 + w] = f2b(v);
      }
    }
    __syncthreads();
    // transposed write-out: 64 rows x 36 chunks of 16B = 2304 chunks
#pragma unroll
    for (int i = 0; i < 9; ++i) {
      const int chunk = i * 256 + t;          // 0..2303
      const int hw_r = chunk / 36;
      const int cno = chunk - hw_r * 36;      // 0..35
      unsigned short hbuf[8];
#pragma unroll
      for (int j = 0; j < 8; ++j)
        hbuf[j] = val_lds[(cno * 8 + j) * 67 + hw_r];
      uint4 p;
      p.x = (unsigned)hbuf[0] | ((unsigned)hbuf[1] << 16);
      p.y = (unsigned)hbuf[2] | ((unsigned)hbuf[3] << 16);
      p.z = (unsigned)hbuf[4] | ((unsigned)hbuf[5] << 16);
      p.w = (unsigned)hbuf[6] | ((unsigned)hbuf[7] << 16);
      *(uint4*)(colT + rowbase + (size_t)hw_r * 2304 + cc0 * 9 + cno * 8) = p;
    }
    __syncthreads();
  }
}

// ---------------- kernel 2: bf16 MFMA GEMM  C[b][o][hw] = W[o][ck] . colT[b][hw][ck]
// m97 structure: BM=BN=128, BK=32, 4 waves x (4x4) 16x16x32 frags, global_load_lds.
#define G2L(gsrc, ldst)                                                            \
  __builtin_amdgcn_global_load_lds(                                                \
      (const __attribute__((address_space(1))) void*)(gsrc),                       \
      (__attribute__((address_space(3))) void*)(ldst), 16, 0, 0)

__global__ __launch_bounds__(256) void dcn_gemm(
    const __bf16* __restrict__ wbf, const unsigned short* __restrict__ colT_,
    const float* __restrict__ bias, float* __restrict__ out) {
  const __bf16* colT = (const __bf16*)colT_;
  // bijective remap: XCD x gets 32 consecutive ids -> panel-sharing mt pairs stay local
  const int id = ((blockIdx.x & 7) << 5) | (blockIdx.x >> 3);
  const int b = id >> 6;
  const int mt = id & 1;
  const int nt = (id >> 1) & 31;

  const int t = threadIdx.x;
  const int wave = t >> 6;
  const int lane = t & 63;
  const int wm = wave >> 1, wn = wave & 1;
  const int lh = lane & 15, lg = lane >> 4;

  __shared__ __align__(16) __bf16 As[128 * 32];
  __shared__ __align__(16) __bf16 Bs[128 * 32];

  const int chunk0 = wave * 64 + lane;   // 0..255
  const int chunk1 = chunk0 + 256;       // 256..511
  const int row0 = chunk0 >> 2, ko0 = (chunk0 & 3) * 8;
  const int row1 = chunk1 >> 2, ko1 = (chunk1 & 3) * 8;

  const __bf16* Abase = wbf + (size_t)(mt * 128) * 2304;
  const __bf16* Bbase = colT + ((size_t)b * 4096 + (size_t)nt * 128) * 2304;
  const __bf16* a0 = Abase + (size_t)row0 * 2304 + ko0;
  const __bf16* a1 = Abase + (size_t)row1 * 2304 + ko1;
  const __bf16* b0 = Bbase + (size_t)row0 * 2304 + ko0;
  const __bf16* b1 = Bbase + (size_t)row1 * 2304 + ko1;
  __bf16* la0 = As + chunk0 * 8;
  __bf16* la1 = As + chunk1 * 8;
  __bf16* lb0 = Bs + chunk0 * 8;
  __bf16* lb1 = Bs + chunk1 * 8;

  const __bf16* ap = As + (wm * 64 + lh) * 32 + lg * 8;
  const __bf16* bp = Bs + (wn * 64 + lh) * 32 + lg * 8;

  f32x4 acc[4][4] = {};

  for (int kt = 0; kt < 72; ++kt) {
    G2L(a0, la0);
    G2L(a1, la1);
    G2L(b0, lb0);
    G2L(b1, lb1);
    __syncthreads();

    bf16x8 af[4], bfv[4];
#pragma unroll
    for (int fm = 0; fm < 4; ++fm) af[fm] = *(const bf16x8*)(ap + fm * 16 * 32);
#pragma unroll
    for (int fn = 0; fn < 4; ++fn) bfv[fn] = *(const bf16x8*)(bp + fn * 16 * 32);
#pragma unroll
    for (int fm = 0; fm < 4; ++fm)
#pragma unroll
      for (int fn = 0; fn < 4; ++fn)
        acc[fm][fn] = __builtin_amdgcn_mfma_f32_16x16x32_bf16(af[fm], bfv[fn],
                                                              acc[fm][fn], 0, 0, 0);
    __syncthreads();
    a0 += 32; a1 += 32; b0 += 32; b1 += 32;
  }

  // epilogue: C/D layout col=lane&15, row=(lane>>4)*4+reg
  float* outb = out + (size_t)b * 256 * 4096;
#pragma unroll
  for (int fm = 0; fm < 4; ++fm) {
#pragma unroll
    for (int i = 0; i < 4; ++i) {
      const int o = mt * 128 + wm * 64 + fm * 16 + lg * 4 + i;
      const float bs = bias[o];
      float* orow = outb + (size_t)o * 4096 + nt * 128 + wn * 64 + lh;
#pragma unroll
      for (int fn = 0; fn < 4; ++fn) orow[fn * 16] = acc[fm][fn][i] + bs;
    }
  }
}

extern "C" void kernel_launch(void* const* d_in, const int* in_sizes, int n_in,
                              void* d_out, int out_size, void* d_ws, size_t ws_size,
                              hipStream_t stream) {
  const float* x = (const float*)d_in[0];
  const float* off = (const float*)d_in[1];
  const float* mask = (const float*)d_in[2];
  const float* wgt = (const float*)d_in[3];
  const float* bias = (const float*)d_in[4];
  float* out = (float*)d_out;

  unsigned short* colT = (unsigned short*)d_ws;             // 4*4096*2304 bf16 = 72 MB
  unsigned short* wbf = colT + 37748736ull;                 // 256*2304 bf16

  cast_weight<<<576, 256, 0, stream>>>(wgt, wbf);
  dcn_sample<<<1024, 256, 0, stream>>>(x, off, mask, colT);
  dcn_gemm<<<256, 256, 0, stream>>>((const __bf16*)wbf, colT, bias, out);
}

// Round 2
// 94.217 us; speedup vs baseline: 2.2622x; 2.2622x over previous
//
#include <hip/hip_runtime.h>

typedef __bf16 bf16x8 __attribute__((ext_vector_type(8)));
typedef float f32x4 __attribute__((ext_vector_type(4)));

__device__ __forceinline__ unsigned short f2b(float f) {
  union { float f; unsigned int u; } v;
  v.f = f;
  unsigned int r = v.u + 0x7fffu + ((v.u >> 16) & 1u);
  return (unsigned short)(r >> 16);
}
__device__ __forceinline__ float b2f(unsigned short u) {
  union { unsigned int u; float f; } v;
  v.u = ((unsigned)u) << 16;
  return v.f;
}

// ---------------- kernel 0: weight f32 [O][C][9] -> bf16 k-major [O][k*256+c] --
__global__ __launch_bounds__(256) void cast_weight(
    const float* __restrict__ w, unsigned short* __restrict__ wb) {
  int idx = blockIdx.x * 256 + threadIdx.x;  // 589824
  int o = idx / 2304;
  int r = idx - o * 2304;
  int k = r >> 8;
  int c = r & 255;
  wb[idx] = f2b(w[(size_t)(o * 256 + c) * 9 + k]);
}

// ---------------- kernel 1: x NCHW f32 -> NHWC bf16  x_t[b][h][w][c] ----------
__global__ __launch_bounds__(256) void transpose_x(
    const float* __restrict__ x, unsigned short* __restrict__ xt) {
  const int b = blockIdx.x >> 6;
  const int h = blockIdx.x & 63;
  const int t = threadIdx.x;
  const int wave = t >> 6, lane = t & 63;
  __shared__ float lds[64][65];
  const int wpos = t >> 2, sub = t & 3;
  const int cl0 = wave * 4 + (lane >> 4);
  const int w0 = (lane & 15) * 4;
  for (int cq = 0; cq < 4; ++cq) {
#pragma unroll
    for (int iter = 0; iter < 4; ++iter) {
      const int cl = iter * 16 + cl0;
      const int c = cq * 64 + cl;
      float4 v = *(const float4*)(x + (((size_t)b * 256 + c) * 64 + h) * 64 + w0);
      lds[cl][w0] = v.x; lds[cl][w0 + 1] = v.y;
      lds[cl][w0 + 2] = v.z; lds[cl][w0 + 3] = v.w;
    }
    __syncthreads();
    unsigned short hb[16];
#pragma unroll
    for (int j = 0; j < 16; ++j) hb[j] = f2b(lds[sub * 16 + j][wpos]);
    uint4 p0, p1;
    p0.x = (unsigned)hb[0] | ((unsigned)hb[1] << 16);
    p0.y = (unsigned)hb[2] | ((unsigned)hb[3] << 16);
    p0.z = (unsigned)hb[4] | ((unsigned)hb[5] << 16);
    p0.w = (unsigned)hb[6] | ((unsigned)hb[7] << 16);
    p1.x = (unsigned)hb[8] | ((unsigned)hb[9] << 16);
    p1.y = (unsigned)hb[10] | ((unsigned)hb[11] << 16);
    p1.z = (unsigned)hb[12] | ((unsigned)hb[13] << 16);
    p1.w = (unsigned)hb[14] | ((unsigned)hb[15] << 16);
    unsigned short* dst = xt + (((size_t)b * 64 + h) * 64 + wpos) * 256 + cq * 64 + sub * 16;
    *(uint4*)dst = p0;
    *(uint4*)(dst + 8) = p1;
    __syncthreads();
  }
}

// ---------------- kernel 2: bilinear sample + mask -> colT[pos][k*256+c] bf16 -
// one wave per output position; lanes across channels (x_t is c-contiguous).
__global__ __launch_bounds__(256) void dcn_sample2(
    const unsigned short* __restrict__ xt, const float* __restrict__ off,
    const float* __restrict__ mask, unsigned short* __restrict__ colT) {
  const int bid = ((blockIdx.x & 7) << 7) | (blockIdx.x >> 3);  // XCD-contiguous
  const int wave = threadIdx.x >> 6;
  const int lane = threadIdx.x & 63;
  const int pos0 = bid * 16 + wave * 4;
  for (int p = 0; p < 4; ++p) {
    const int pos = pos0 + p;
    const int b = pos >> 12;
    const int hw = pos & 4095;
    const int h = hw >> 6;
    const int w = hw & 63;
    const float* offp = off + (size_t)b * 18 * 4096 + hw;
    const float* mp = mask + (size_t)b * 9 * 4096 + hw;
    const unsigned short* xb = xt + (size_t)b * 64 * 64 * 256 + lane * 4;
    unsigned short* cp = colT + (size_t)pos * 2304 + lane * 4;
#pragma unroll
    for (int k = 0; k < 9; ++k) {
      float oy = offp[(2 * k) * 4096];
      float ox = offp[(2 * k + 1) * 4096];
      float m = mp[k * 4096];
      float py = oy + (float)(h - 1 + k / 3);
      float px = ox + (float)(w - 1 + k % 3);
      float y0f = floorf(py), x0f = floorf(px);
      float ly = py - y0f, lx = px - x0f;
      float hy = 1.f - ly, hx = 1.f - lx;
      int y0 = (int)y0f, x0 = (int)x0f;
      int y1 = y0 + 1, x1 = x0 + 1;
      bool vy0 = (y0 >= 0) && (y0 < 64);
      bool vy1 = (y1 >= 0) && (y1 < 64);
      bool vx0 = (x0 >= 0) && (x0 < 64);
      bool vx1 = (x1 >= 0) && (x1 < 64);
      int yc0 = min(max(y0, 0), 63), yc1 = min(max(y1, 0), 63);
      int xc0 = min(max(x0, 0), 63), xc1 = min(max(x1, 0), 63);
      float w00 = (vy0 && vx0) ? hy * hx * m : 0.f;
      float w01 = (vy0 && vx1) ? hy * lx * m : 0.f;
      float w10 = (vy1 && vx0) ? ly * hx * m : 0.f;
      float w11 = (vy1 && vx1) ? ly * lx * m : 0.f;
      uint2 t00 = *(const uint2*)(xb + (yc0 * 64 + xc0) * 256);
      uint2 t01 = *(const uint2*)(xb + (yc0 * 64 + xc1) * 256);
      uint2 t10 = *(const uint2*)(xb + (yc1 * 64 + xc0) * 256);
      uint2 t11 = *(const uint2*)(xb + (yc1 * 64 + xc1) * 256);
      float v0 = w00 * b2f((unsigned short)t00.x) + w01 * b2f((unsigned short)t01.x) +
                 w10 * b2f((unsigned short)t10.x) + w11 * b2f((unsigned short)t11.x);
      float v1 = w00 * b2f((unsigned short)(t00.x >> 16)) + w01 * b2f((unsigned short)(t01.x >> 16)) +
                 w10 * b2f((unsigned short)(t10.x >> 16)) + w11 * b2f((unsigned short)(t11.x >> 16));
      float v2 = w00 * b2f((unsigned short)t00.y) + w01 * b2f((unsigned short)t01.y) +
                 w10 * b2f((unsigned short)t10.y) + w11 * b2f((unsigned short)t11.y);
      float v3 = w00 * b2f((unsigned short)(t00.y >> 16)) + w01 * b2f((unsigned short)(t01.y >> 16)) +
                 w10 * b2f((unsigned short)(t10.y >> 16)) + w11 * b2f((unsigned short)(t11.y >> 16));
      uint2 r;
      r.x = (unsigned)f2b(v0) | ((unsigned)f2b(v1) << 16);
      r.y = (unsigned)f2b(v2) | ((unsigned)f2b(v3) << 16);
      *(uint2*)(cp + k * 256) = r;
    }
  }
}

// ---------------- kernel 3: bf16 MFMA GEMM  out[b][o][hw] = W[o][K] . colT[b*hw][K]
// BM=128, BN=64, BK=32; grid 512 (2 blocks/CU); 4 waves (2m x 2n), 4x2 frags.
#define G2L(gsrc, ldst)                                                            \
  __builtin_amdgcn_global_load_lds(                                                \
      (const __attribute__((address_space(1))) void*)(gsrc),                       \
      (__attribute__((address_space(3))) void*)(ldst), 16, 0, 0)

__global__ __launch_bounds__(256) void dcn_gemm(
    const __bf16* __restrict__ wbf, const unsigned short* __restrict__ colT_,
    const float* __restrict__ bias, float* __restrict__ out) {
  const __bf16* colT = (const __bf16*)colT_;
  const int id = ((blockIdx.x & 7) << 6) | (blockIdx.x >> 3);  // bijective, 512
  const int mt = id & 1;
  const int ntg = id >> 1;      // 0..255
  const int b = ntg >> 6;
  const int nt = ntg & 63;

  const int t = threadIdx.x;
  const int wave = t >> 6;
  const int lane = t & 63;
  const int wm = wave >> 1, wn = wave & 1;
  const int lh = lane & 15, lg = lane >> 4;

  __shared__ __align__(16) __bf16 As[128 * 32];
  __shared__ __align__(16) __bf16 Bs[64 * 32];

  const int chunk0 = t;            // A rows 0..63
  const int chunk1 = t + 256;      // A rows 64..127
  const int rowA0 = chunk0 >> 2, koA0 = (chunk0 & 3) * 8;
  const int rowA1 = chunk1 >> 2, koA1 = (chunk1 & 3) * 8;
  const int rowB = t >> 2, koB = (t & 3) * 8;

  const __bf16* Abase = wbf + (size_t)(mt * 128) * 2304;
  const __bf16* Bbase = colT + ((size_t)b * 4096 + (size_t)nt * 64) * 2304;
  const __bf16* a0 = Abase + (size_t)rowA0 * 2304 + koA0;
  const __bf16* a1 = Abase + (size_t)rowA1 * 2304 + koA1;
  const __bf16* bg = Bbase + (size_t)rowB * 2304 + koB;
  __bf16* la0 = As + chunk0 * 8;
  __bf16* la1 = As + chunk1 * 8;
  __bf16* lb = Bs + t * 8;

  const __bf16* ap = As + (wm * 64 + lh) * 32 + lg * 8;
  const __bf16* bp = Bs + (wn * 32 + lh) * 32 + lg * 8;

  f32x4 acc[4][2] = {};

  for (int kt = 0; kt < 72; ++kt) {
    G2L(a0, la0);
    G2L(a1, la1);
    G2L(bg, lb);
    __syncthreads();

    bf16x8 af[4], bfv[2];
#pragma unroll
    for (int fm = 0; fm < 4; ++fm) af[fm] = *(const bf16x8*)(ap + fm * 16 * 32);
#pragma unroll
    for (int fn = 0; fn < 2; ++fn) bfv[fn] = *(const bf16x8*)(bp + fn * 16 * 32);
#pragma unroll
    for (int fm = 0; fm < 4; ++fm)
#pragma unroll
      for (int fn = 0; fn < 2; ++fn)
        acc[fm][fn] = __builtin_amdgcn_mfma_f32_16x16x32_bf16(af[fm], bfv[fn],
                                                              acc[fm][fn], 0, 0, 0);
    __syncthreads();
    a0 += 32; a1 += 32; bg += 32;
  }

  float* outb = out + (size_t)b * 256 * 4096;
#pragma unroll
  for (int fm = 0; fm < 4; ++fm) {
#pragma unroll
    for (int i = 0; i < 4; ++i) {
      const int o = mt * 128 + wm * 64 + fm * 16 + lg * 4 + i;
      const float bs = bias[o];
      float* orow = outb + (size_t)o * 4096 + nt * 64 + wn * 32 + lh;
#pragma unroll
      for (int fn = 0; fn < 2; ++fn) orow[fn * 16] = acc[fm][fn][i] + bs;
    }
  }
}

extern "C" void kernel_launch(void* const* d_in, const int* in_sizes, int n_in,
                              void* d_out, int out_size, void* d_ws, size_t ws_size,
                              hipStream_t stream) {
  const float* x = (const float*)d_in[0];
  const float* off = (const float*)d_in[1];
  const float* mask = (const float*)d_in[2];
  const float* wgt = (const float*)d_in[3];
  const float* bias = (const float*)d_in[4];
  float* out = (float*)d_out;

  unsigned short* colT = (unsigned short*)d_ws;        // 4*4096*2304 bf16 = 72 MB
  unsigned short* wbf = colT + 37748736ull;            // 256*2304 bf16 = 1.2 MB
  unsigned short* xt = wbf + 589824ull;                // 4*64*64*256 bf16 = 16.8 MB

  cast_weight<<<2304, 256, 0, stream>>>(wgt, wbf);
  transpose_x<<<256, 256, 0, stream>>>(x, xt);
  dcn_sample2<<<1024, 256, 0, stream>>>(xt, off, mask, colT);
  dcn_gemm<<<512, 256, 0, stream>>>((const __bf16*)wbf, colT, bias, out);
}

// Round 3
// 72.273 us; speedup vs baseline: 2.9491x; 1.3036x over previous
//
#include <hip/hip_runtime.h>

typedef __bf16 bf16x8 __attribute__((ext_vector_type(8)));
typedef float f32x4 __attribute__((ext_vector_type(4)));

__device__ __forceinline__ unsigned short f2b(float f) {
  union { float f; unsigned int u; } v;
  v.f = f;
  unsigned int r = v.u + 0x7fffu + ((v.u >> 16) & 1u);
  return (unsigned short)(r >> 16);
}
__device__ __forceinline__ float b2f_lo(unsigned int u) {
  union { unsigned int u; float f; } v;
  v.u = u << 16;
  return v.f;
}
__device__ __forceinline__ float b2f_hi(unsigned int u) {
  union { unsigned int u; float f; } v;
  v.u = u & 0xffff0000u;
  return v.f;
}

// ---------------- kernel 0: weight f32 [O][C][9] -> bf16 k-major [O][k*256+c] --
__global__ __launch_bounds__(256) void cast_weight(
    const float* __restrict__ w, unsigned short* __restrict__ wb) {
  int idx = blockIdx.x * 256 + threadIdx.x;  // 589824
  int o = idx / 2304;
  int r = idx - o * 2304;
  int k = r >> 8;
  int c = r & 255;
  wb[idx] = f2b(w[(size_t)(o * 256 + c) * 9 + k]);
}

// ---------------- kernel 1: x NCHW f32 -> NHWC bf16  x_t[b][h][w][c] ----------
__global__ __launch_bounds__(256) void transpose_x(
    const float* __restrict__ x, unsigned short* __restrict__ xt) {
  const int b = blockIdx.x >> 6;
  const int h = blockIdx.x & 63;
  const int t = threadIdx.x;
  const int wave = t >> 6, lane = t & 63;
  __shared__ float lds[64][65];
  const int wpos = t >> 2, sub = t & 3;
  const int cl0 = wave * 4 + (lane >> 4);
  const int w0 = (lane & 15) * 4;
  for (int cq = 0; cq < 4; ++cq) {
#pragma unroll
    for (int iter = 0; iter < 4; ++iter) {
      const int cl = iter * 16 + cl0;
      const int c = cq * 64 + cl;
      float4 v = *(const float4*)(x + (((size_t)b * 256 + c) * 64 + h) * 64 + w0);
      lds[cl][w0] = v.x; lds[cl][w0 + 1] = v.y;
      lds[cl][w0 + 2] = v.z; lds[cl][w0 + 3] = v.w;
    }
    __syncthreads();
    unsigned short hb[16];
#pragma unroll
    for (int j = 0; j < 16; ++j) hb[j] = f2b(lds[sub * 16 + j][wpos]);
    uint4 p0, p1;
    p0.x = (unsigned)hb[0] | ((unsigned)hb[1] << 16);
    p0.y = (unsigned)hb[2] | ((unsigned)hb[3] << 16);
    p0.z = (unsigned)hb[4] | ((unsigned)hb[5] << 16);
    p0.w = (unsigned)hb[6] | ((unsigned)hb[7] << 16);
    p1.x = (unsigned)hb[8] | ((unsigned)hb[9] << 16);
    p1.y = (unsigned)hb[10] | ((unsigned)hb[11] << 16);
    p1.z = (unsigned)hb[12] | ((unsigned)hb[13] << 16);
    p1.w = (unsigned)hb[14] | ((unsigned)hb[15] << 16);
    unsigned short* dst = xt + (((size_t)b * 64 + h) * 64 + wpos) * 256 + cq * 64 + sub * 16;
    *(uint4*)dst = p0;
    *(uint4*)(dst + 8) = p1;
    __syncthreads();
  }
}

// ---------------- fused: sample + GEMM -------------------------------------
// block = (b, nt=h). Out tile [256 o][64 hw]. K = k*256+c, 72 steps of 32.
// 512 threads = 8 waves (4m x 2n). Bs built in-LDS from x_t; As via G2L.
#define G2L(gsrc, ldst)                                                            \
  __builtin_amdgcn_global_load_lds(                                                \
      (const __attribute__((address_space(1))) void*)(gsrc),                       \
      (__attribute__((address_space(3))) void*)(ldst), 16, 0, 0)

__device__ __forceinline__ void load_taps(uint2 q[4], const unsigned short* t0,
                                          const unsigned short* t1,
                                          const unsigned short* t2,
                                          const unsigned short* t3, int eoff) {
  q[0] = *(const uint2*)(t0 + eoff);
  q[1] = *(const uint2*)(t1 + eoff);
  q[2] = *(const uint2*)(t2 + eoff);
  q[3] = *(const uint2*)(t3 + eoff);
}

__device__ __forceinline__ void combine_write(const uint2 q[4], float4 wt,
                                              __bf16* dst) {
  float v0 = wt.x * b2f_lo(q[0].x) + wt.y * b2f_lo(q[1].x) +
             wt.z * b2f_lo(q[2].x) + wt.w * b2f_lo(q[3].x);
  float v1 = wt.x * b2f_hi(q[0].x) + wt.y * b2f_hi(q[1].x) +
             wt.z * b2f_hi(q[2].x) + wt.w * b2f_hi(q[3].x);
  float v2 = wt.x * b2f_lo(q[0].y) + wt.y * b2f_lo(q[1].y) +
             wt.z * b2f_lo(q[2].y) + wt.w * b2f_lo(q[3].y);
  float v3 = wt.x * b2f_hi(q[0].y) + wt.y * b2f_hi(q[1].y) +
             wt.z * b2f_hi(q[2].y) + wt.w * b2f_hi(q[3].y);
  uint2 r;
  r.x = (unsigned)f2b(v0) | ((unsigned)f2b(v1) << 16);
  r.y = (unsigned)f2b(v2) | ((unsigned)f2b(v3) << 16);
  *(uint2*)dst = r;
}

__global__ __launch_bounds__(512) void dcn_fused(
    const unsigned short* __restrict__ xt, const float* __restrict__ off,
    const float* __restrict__ mask, const __bf16* __restrict__ wbf,
    const float* __restrict__ bias, float* __restrict__ out) {
  const int bid = blockIdx.x;
  const int id = ((bid & 7) << 5) | (bid >> 3);  // XCD-contiguous, bijective (256=8*32)
  const int b = id >> 6;
  const int nt = id & 63;  // = h row

  const int tid = threadIdx.x;
  const int lane = tid & 63;
  const int wave = tid >> 6;
  const int wm = wave >> 1, wn = wave & 1;
  const int lh = lane & 15, lg = lane >> 4;

  __shared__ __align__(16) __bf16 As[2][256 * 32];  // 32 KB
  __shared__ __align__(16) __bf16 Bs[2][64 * 32];   // 8 KB
  __shared__ __align__(16) float swt[9][64][4];     // 9 KB
  __shared__ __align__(16) int sidx[9][64][4];      // 9 KB

  // ---- precompute per-(pos,k) tap weights & indices ----
  for (int pair = tid; pair < 576; pair += 512) {
    const int k = pair >> 6;   // 0..8
    const int pl = pair & 63;  // = w
    float oy = off[(((size_t)b * 18 + 2 * k) * 64 + nt) * 64 + pl];
    float ox = off[(((size_t)b * 18 + 2 * k + 1) * 64 + nt) * 64 + pl];
    float m = mask[(((size_t)b * 9 + k) * 64 + nt) * 64 + pl];
    float py = oy + (float)(nt - 1 + k / 3);
    float px = ox + (float)(pl - 1 + k % 3);
    float y0f = floorf(py), x0f = floorf(px);
    float ly = py - y0f, lx = px - x0f;
    float hy = 1.f - ly, hx = 1.f - lx;
    int y0 = (int)y0f, x0 = (int)x0f;
    int y1 = y0 + 1, x1 = x0 + 1;
    bool vy0 = (y0 >= 0) && (y0 < 64);
    bool vy1 = (y1 >= 0) && (y1 < 64);
    bool vx0 = (x0 >= 0) && (x0 < 64);
    bool vx1 = (x1 >= 0) && (x1 < 64);
    int yc0 = min(max(y0, 0), 63), yc1 = min(max(y1, 0), 63);
    int xc0 = min(max(x0, 0), 63), xc1 = min(max(x1, 0), 63);
    sidx[k][pl][0] = (yc0 * 64 + xc0) * 256;
    sidx[k][pl][1] = (yc0 * 64 + xc1) * 256;
    sidx[k][pl][2] = (yc1 * 64 + xc0) * 256;
    sidx[k][pl][3] = (yc1 * 64 + xc1) * 256;
    swt[k][pl][0] = (vy0 && vx0) ? hy * hx * m : 0.f;
    swt[k][pl][1] = (vy0 && vx1) ? hy * lx * m : 0.f;
    swt[k][pl][2] = (vy1 && vx0) ? ly * hx * m : 0.f;
    swt[k][pl][3] = (vy1 && vx1) ? ly * lx * m : 0.f;
  }

  // staging geometry
  const int rowA0 = tid >> 2, koA = (tid & 3) * 8;
  const __bf16* aP0 = wbf + (size_t)rowA0 * 2304 + koA;
  const __bf16* aP1 = wbf + (size_t)(rowA0 + 128) * 2304 + koA;

  const int pos = tid >> 3, ci = tid & 7;
  const unsigned short* xtb = xt + (size_t)b * 1048576 + ci * 4;

  f32x4 acc[4][2] = {};
  uint2 qA[4], qB[4];
  float4 wt4;
  const unsigned short *t0, *t1, *t2, *t3;

  __syncthreads();  // swt/sidx ready

  // ---- prologue: step 0 build + taps(1) prefetch ----
  {
    wt4 = *(const float4*)&swt[0][pos][0];
    int4 ix = *(const int4*)&sidx[0][pos][0];
    t0 = xtb + ix.x; t1 = xtb + ix.y; t2 = xtb + ix.z; t3 = xtb + ix.w;
    load_taps(qA, t0, t1, t2, t3, 0);
    combine_write(qA, wt4, &Bs[0][pos * 32 + ci * 4]);
    G2L(aP0, &As[0][tid * 8]);
    G2L(aP1, &As[0][(tid + 512) * 8]);
    load_taps(qB, t0, t1, t2, t3, 32);
  }
  __syncthreads();  // barrier(0): As[0], Bs[0] valid

  for (int k = 0; k < 9; ++k) {
#pragma unroll
    for (int cb = 0; cb < 8; ++cb) {
      const int kt = k * 8 + cb;
      const int p = cb & 1;
      // A prefetch for step kt+1
      if (kt < 71) {
        G2L(aP0 + (kt + 1) * 32, &As[p ^ 1][tid * 8]);
        G2L(aP1 + (kt + 1) * 32, &As[p ^ 1][(tid + 512) * 8]);
      }
      // tap prefetch (within k): step kt+2
      if (cb < 6) {
        if ((cb & 1) == 0) load_taps(qA, t0, t1, t2, t3, (cb + 2) * 32);
        else               load_taps(qB, t0, t1, t2, t3, (cb + 2) * 32);
      }
      // combine for step kt+1 (same k)
      if (cb < 7) {
        if ((cb & 1) == 0) combine_write(qB, wt4, &Bs[1][pos * 32 + ci * 4]);
        else               combine_write(qA, wt4, &Bs[0][pos * 32 + ci * 4]);
      }
      if (cb == 7 && k < 8) {
        // next-k pointer setup + taps((k+1)*8) load (issued before MFMA for cover)
        wt4 = *(const float4*)&swt[k + 1][pos][0];
        int4 ix = *(const int4*)&sidx[k + 1][pos][0];
        t0 = xtb + ix.x; t1 = xtb + ix.y; t2 = xtb + ix.z; t3 = xtb + ix.w;
        load_taps(qA, t0, t1, t2, t3, 0);
      }
      // MFMA step kt
      {
        const __bf16* app = &As[p][(wm * 64 + lh) * 32 + lg * 8];
        const __bf16* bpp = &Bs[p][(wn * 32 + lh) * 32 + lg * 8];
        bf16x8 af[4], bf2[2];
#pragma unroll
        for (int fm = 0; fm < 4; ++fm) af[fm] = *(const bf16x8*)(app + fm * 16 * 32);
#pragma unroll
        for (int fn = 0; fn < 2; ++fn) bf2[fn] = *(const bf16x8*)(bpp + fn * 16 * 32);
#pragma unroll
        for (int fm = 0; fm < 4; ++fm)
#pragma unroll
          for (int fn = 0; fn < 2; ++fn)
            acc[fm][fn] = __builtin_amdgcn_mfma_f32_16x16x32_bf16(
                af[fm], bf2[fn], acc[fm][fn], 0, 0, 0);
      }
      if (cb == 7 && k < 8) {
        combine_write(qA, wt4, &Bs[0][pos * 32 + ci * 4]);  // step (k+1)*8
        load_taps(qB, t0, t1, t2, t3, 32);                  // taps((k+1)*8+1)
      }
      if (kt < 71) __syncthreads();
    }
  }

  // ---- epilogue ----
  float* outb = out + (size_t)b * 256 * 4096 + (size_t)nt * 64;
#pragma unroll
  for (int fm = 0; fm < 4; ++fm) {
#pragma unroll
    for (int i = 0; i < 4; ++i) {
      const int o = wm * 64 + fm * 16 + lg * 4 + i;
      const float bs = bias[o];
      float* orow = outb + (size_t)o * 4096 + wn * 32 + lh;
#pragma unroll
      for (int fn = 0; fn < 2; ++fn) orow[fn * 16] = acc[fm][fn][i] + bs;
    }
  }
}

extern "C" void kernel_launch(void* const* d_in, const int* in_sizes, int n_in,
                              void* d_out, int out_size, void* d_ws, size_t ws_size,
                              hipStream_t stream) {
  const float* x = (const float*)d_in[0];
  const float* off = (const float*)d_in[1];
  const float* mask = (const float*)d_in[2];
  const float* wgt = (const float*)d_in[3];
  const float* bias = (const float*)d_in[4];
  float* out = (float*)d_out;

  unsigned short* wbf = (unsigned short*)d_ws;   // 256*2304 bf16 = 1.2 MB
  unsigned short* xt = wbf + 589824ull;          // 4*64*64*256 bf16 = 8.4 MB

  cast_weight<<<2304, 256, 0, stream>>>(wgt, wbf);
  transpose_x<<<256, 256, 0, stream>>>(x, xt);
  dcn_fused<<<256, 512, 0, stream>>>(xt, off, mask, (const __bf16*)wbf, bias, out);
}